// Round 2
// baseline (14702.759 us; speedup 1.0000x reference)
//
#include <hip/hip_runtime.h>
#include <math.h>

#define NB 4
#define CE 384
#define NH 12
#define DH 32
#define NPTS 9
#define NLAYERS 2
#define KFG 20
#define KBG 50
#define NITER 10
#define HDIM 64
#define WDIM 64
#define NPIX 4096
#define TWO_PI 6.283185307179586f

// ---------------- masks ----------------
__global__ void k_masks(const float* __restrict__ pm, const float* __restrict__ sm,
                        float* padf, float* objf, float* notp, float* wfg, float* wbg) {
  int i = blockIdx.x * 256 + threadIdx.x;
  if (i >= NB * NPIX) return;
  float p  = (pm[i] == 255.0f) ? 1.f : 0.f;
  float o  = (sm[i] == 1.0f) ? 1.f : 0.f;
  float np_ = 1.f - p;
  padf[i] = p; objf[i] = o; notp[i] = np_;
  wfg[i] = o * np_;
  wbg[i] = (1.f - o) * np_;
}

// ---------------- transpose s_x [B,C,N] -> X [B,N,C] ----------------
__global__ void k_transpose(const float* __restrict__ sx, float* __restrict__ X) {
  long i = (long)blockIdx.x * 256 + threadIdx.x;
  if (i >= (long)NB * NPIX * CE) return;
  int c = (int)(i % CE);
  long r = i / CE;
  int n = (int)(r % NPIX);
  int b = (int)(r / NPIX);
  X[i] = sx[((long)b * CE + c) * NPIX + n];
}

// ---------------- xsq (fp64) ----------------
__global__ void k_xsq(const float* __restrict__ X, double* __restrict__ xsq) {
  int row = blockIdx.x; int t = threadIdx.x;
  const float* xr = X + (long)row * CE;
  double s = 0.0;
  for (int i = t; i < CE; i += 64) { double v = (double)xr[i]; s += v * v; }
  #pragma unroll
  for (int o = 32; o > 0; o >>= 1) s += __shfl_down(s, o, 64);
  if (t == 0) xsq[row] = s;
}

// ---------------- sine positional encoding ----------------
__global__ void k_pos(const float* __restrict__ padf, float* __restrict__ POS) {
  int b = blockIdx.x / HDIM, hh = blockIdx.x % HDIM;
  __shared__ float xv[WDIM], yv[WDIM];
  int t = threadIdx.x;
  if (t < WDIM) {
    int w = t;
    float cum = 0.f, tot = 0.f;
    for (int h2 = 0; h2 < HDIM; ++h2) {
      float nm = 1.f - padf[b * NPIX + h2 * WDIM + w];
      tot += nm;
      if (h2 <= hh) cum += nm;
    }
    yv[w] = cum / (tot + 1e-6f) * TWO_PI;
    float rtot = 0.f, myc = 0.f;
    for (int w2 = 0; w2 < WDIM; ++w2) {
      float nm = 1.f - padf[b * NPIX + hh * WDIM + w2];
      rtot += nm;
      if (w2 <= w) myc += nm;
    }
    xv[w] = myc / (rtot + 1e-6f) * TWO_PI;
  }
  __syncthreads();
  const int nf = CE / 2;  // 192
  for (int i = t; i < WDIM * CE; i += 256) {
    int w = i / CE, c = i % CE;
    int tt = (c < nf) ? c : c - nf;
    float p = (c < nf) ? yv[w] : xv[w];
    float dt = powf(10000.0f, (float)(2 * (tt / 2)) / (float)nf);
    float v = p / dt;
    float r = (tt & 1) ? cosf(v) : sinf(v);
    POS[((long)(b * NPIX + hh * WDIM)) * CE + i] = r;
  }
}

// ---------------- kmeans init: first-K in-group (then earliest out-group) ----------------
__global__ void k_kinit(const float* __restrict__ X, const float* __restrict__ wts,
                        double* __restrict__ cen, int K) {
  int b = blockIdx.x;
  __shared__ int idx[KBG];
  if (threadIdx.x == 0) {
    int cnt = 0;
    for (int n = 0; n < NPIX && cnt < K; ++n) if (wts[b * NPIX + n] > 0.f) idx[cnt++] = n;
    for (int n = 0; n < NPIX && cnt < K; ++n) if (!(wts[b * NPIX + n] > 0.f)) idx[cnt++] = n;
  }
  __syncthreads();
  for (int i = threadIdx.x; i < K * CE; i += blockDim.x) {
    int k = i / CE, c = i % CE;
    cen[((long)b * K + k) * CE + c] = (double)X[((long)b * NPIX + idx[k]) * CE + c];
  }
}

__global__ void k_zero64(double* a, double* b, int na, int nbn) {
  int i = blockIdx.x * 256 + threadIdx.x;
  if (i < na) a[i] = 0.0;
  else if (i - na < nbn) b[i - na] = 0.0;
}

// ---------------- kmeans assign + accumulate (fp64 exact) ----------------
template <int K, int KC>
__global__ __launch_bounds__(256) void k_assign_acc(
    const float* __restrict__ X, const float* __restrict__ wts,
    const double* __restrict__ xsq, const double* __restrict__ cen,
    double* __restrict__ num, double* __restrict__ den) {
  int b = blockIdx.y;
  int n0 = blockIdx.x * 256;
  int t = threadIdx.x;
  int n = n0 + t;
  __shared__ double csq[K];
  __shared__ double ct[KC][33];
  __shared__ float xt[256][36];
  const double* cb = cen + (long)b * K * CE;
  if (t < K) {
    double s = 0.0;
    for (int c = 0; c < CE; ++c) { double v = cb[t * CE + c]; s += v * v; }
    csq[t] = s;
  }
  double best = 1.0e300; int bi = 0;
  for (int kc = 0; kc < K; kc += KC) {
    int kn = (K - kc < KC) ? (K - kc) : KC;
    double acc[KC];
    #pragma unroll
    for (int k = 0; k < KC; ++k) acc[k] = 0.0;
    for (int c0 = 0; c0 < CE; c0 += 32) {
      __syncthreads();
      for (int i = t; i < 256 * 32; i += 256) {
        int rr = i >> 5, cc = i & 31;
        xt[rr][cc] = X[((long)b * NPIX + n0 + rr) * CE + c0 + cc];
      }
      for (int i = t; i < KC * 32; i += 256) {
        int k = i >> 5, cc = i & 31;
        if (k < kn) ct[k][cc] = cb[(long)(kc + k) * CE + c0 + cc];
      }
      __syncthreads();
      for (int cc = 0; cc < 32; ++cc) {
        double xv = (double)xt[t][cc];
        #pragma unroll
        for (int k = 0; k < KC; ++k) acc[k] += xv * ct[k][cc];
      }
    }
    double myxsq = xsq[b * NPIX + n];
    for (int k = 0; k < kn; ++k) {
      double d = myxsq - 2.0 * acc[k] + csq[kc + k];
      if (d < best) { best = d; bi = kc + k; }
    }
  }
  float w = wts[b * NPIX + n];
  if (w > 0.f) {
    atomicAdd(&den[b * K + bi], 1.0);
    const float* xr = X + ((long)b * NPIX + n) * CE;
    double* nr = num + ((long)(b * K + bi)) * CE;
    for (int c = 0; c < CE; ++c) atomicAdd(&nr[c], (double)xr[c]);
  }
}

__global__ void k_final(const double* __restrict__ num, const double* __restrict__ den,
                        const double* __restrict__ cOld, double* __restrict__ cNew, int total) {
  int i = blockIdx.x * 256 + threadIdx.x;
  if (i >= total) return;
  double d = den[i / CE];
  cNew[i] = (d > 0.0) ? num[i] / fmax(d, 1e-6) : cOld[i];
}

// ---------------- generic fp32 GEMM: C = op(A) @ W (+bias)(+relu) ----------------
__global__ __launch_bounds__(256) void k_gemm(
    const float* __restrict__ A, const float* __restrict__ A2, const float* __restrict__ rs,
    const float* __restrict__ W, const float* __restrict__ bias, float* __restrict__ C,
    int M, int K, int Nn, int act) {
  __shared__ float As[16][65];
  __shared__ float Bs[16][65];
  int m0 = blockIdx.y * 64, n0 = blockIdx.x * 64;
  int t = threadIdx.x;
  int tn = t & 15, tm = t >> 4;
  float acc[4][4] = {};
  for (int k0 = 0; k0 < K; k0 += 16) {
    for (int i = t; i < 64 * 16; i += 256) {
      int r = i >> 4, kk = i & 15;
      long ai = (long)(m0 + r) * K + k0 + kk;
      float v = A[ai];
      if (A2) v += A2[ai];
      if (rs) v *= rs[m0 + r];
      As[kk][r] = v;
    }
    for (int i = t; i < 16 * 64; i += 256) {
      int kk = i >> 6, nn = i & 63;
      int col = n0 + nn;
      Bs[kk][nn] = (col < Nn) ? W[(long)(k0 + kk) * Nn + col] : 0.f;
    }
    __syncthreads();
    #pragma unroll
    for (int kk = 0; kk < 16; ++kk) {
      float av[4], bv[4];
      #pragma unroll
      for (int i = 0; i < 4; ++i) av[i] = As[kk][tm + 16 * i];
      #pragma unroll
      for (int j = 0; j < 4; ++j) bv[j] = Bs[kk][tn + 16 * j];
      #pragma unroll
      for (int i = 0; i < 4; ++i)
        #pragma unroll
        for (int j = 0; j < 4; ++j) acc[i][j] += av[i] * bv[j];
    }
    __syncthreads();
  }
  #pragma unroll
  for (int i = 0; i < 4; ++i) {
    int m = m0 + tm + 16 * i;
    #pragma unroll
    for (int j = 0; j < 4; ++j) {
      int n = n0 + tn + 16 * j;
      if (n < Nn) {
        float v = acc[i][j];
        if (bias) v += bias[n];
        if (act) v = fmaxf(v, 0.f);
        C[(long)m * Nn + n] = v;
      }
    }
  }
}

// ---------------- softmax over 9 points ----------------
__global__ void k_softmax(float* __restrict__ aw) {
  long i = (long)blockIdx.x * 256 + threadIdx.x;
  if (i >= (long)NB * NPIX * NH) return;
  float* p = aw + i * NPTS;
  float m = p[0];
  #pragma unroll
  for (int j = 1; j < NPTS; ++j) m = fmaxf(m, p[j]);
  float e[NPTS]; float s = 0.f;
  #pragma unroll
  for (int j = 0; j < NPTS; ++j) { e[j] = expf(p[j] - m); s += e[j]; }
  float inv = 1.f / s;
  #pragma unroll
  for (int j = 0; j < NPTS; ++j) p[j] = e[j] * inv;
}

// ---------------- bilinear sampler + point-weighted sum ----------------
__device__ __forceinline__ float sampleV(const float* __restrict__ vb, int xi, int yi, int c) {
  bool valid = (xi >= 0) & (xi < WDIM) & (yi >= 0) & (yi < HDIM);
  int xc = min(max(xi, 0), WDIM - 1), yc = min(max(yi, 0), HDIM - 1);
  float g = vb[(long)(yc * WDIM + xc) * CE + c];
  return valid ? g : 0.f;
}

__global__ void k_sample(const float* __restrict__ V, const float* __restrict__ OFF,
                         const float* __restrict__ AW, float* __restrict__ ATT) {
  long gid = (long)blockIdx.x * 256 + threadIdx.x;
  if (gid >= (long)NB * NPIX * CE) return;
  int c = (int)(gid % CE);
  long r = gid / CE;
  int n = (int)(r % NPIX);
  int b = (int)(r / NPIX);
  int h = c >> 5;
  int hh = n >> 6, ww = n & 63;
  const float* offp = OFF + ((long)(b * NPIX + n)) * 216 + h * 18;
  const float* awp  = AW  + ((long)(b * NPIX + n)) * 108 + h * 9;
  const float* vb = V + ((long)b * NPIX) * CE;
  float refx = ((float)ww + 0.5f) / (float)WDIM;
  float refy = ((float)hh + 0.5f) / (float)HDIM;
  float acc = 0.f;
  #pragma unroll
  for (int p = 0; p < NPTS; ++p) {
    float ox = offp[p * 2 + 0], oy = offp[p * 2 + 1];
    float lx = refx + ox / (float)WDIM;
    float ly = refy + oy / (float)HDIM;
    float xs = lx * (float)WDIM - 0.5f;
    float ys = ly * (float)HDIM - 0.5f;
    float x0f = floorf(xs), y0f = floorf(ys);
    float wx = xs - x0f, wy = ys - y0f;
    int x0 = (int)x0f, y0 = (int)y0f;
    float g00 = sampleV(vb, x0,     y0,     c);
    float g01 = sampleV(vb, x0 + 1, y0,     c);
    float g10 = sampleV(vb, x0,     y0 + 1, c);
    float g11 = sampleV(vb, x0 + 1, y0 + 1, c);
    float bil = g00 * (1.f - wx) * (1.f - wy) + g01 * wx * (1.f - wy)
              + g10 * (1.f - wx) * wy + g11 * wx * wy;
    acc += awp[p] * bil;
  }
  ATT[gid] = acc;
}

// ---------------- LayerNorm(X + T) -> X (in place), one wave per row ----------------
__global__ void k_ln(float* __restrict__ X, const float* __restrict__ T,
                     const float* __restrict__ g, const float* __restrict__ bb) {
  int row = blockIdx.x; int t = threadIdx.x;
  float* xr = X + (long)row * CE;
  const float* tr = T + (long)row * CE;
  float v[6]; float s = 0.f;
  #pragma unroll
  for (int i = 0; i < 6; ++i) { v[i] = xr[t + 64 * i] + tr[t + 64 * i]; s += v[i]; }
  #pragma unroll
  for (int o = 32; o > 0; o >>= 1) s += __shfl_down(s, o, 64);
  s = __shfl(s, 0, 64);
  float m = s / (float)CE;
  float var = 0.f;
  #pragma unroll
  for (int i = 0; i < 6; ++i) { float d = v[i] - m; var += d * d; }
  #pragma unroll
  for (int o = 32; o > 0; o >>= 1) var += __shfl_down(var, o, 64);
  var = __shfl(var, 0, 64);
  float rst = rsqrtf(var / (float)CE + 1e-5f);
  #pragma unroll
  for (int i = 0; i < 6; ++i) { int c = t + 64 * i; xr[c] = (v[i] - m) * rst * g[c] + bb[c]; }
}

// ---------------- assemble output ----------------
__global__ void k_out(const float* __restrict__ X, const double* __restrict__ fg,
                      const double* __restrict__ bg, float* __restrict__ out) {
  long i = (long)blockIdx.x * 256 + threadIdx.x;
  const long tot = (long)NB * (NPIX + KFG + KBG) * CE;
  if (i >= tot) return;
  int c = (int)(i % CE);
  long r = i / CE;
  int rr = (int)(r % (NPIX + KFG + KBG));
  int b = (int)(r / (NPIX + KFG + KBG));
  float v;
  if (rr < NPIX) v = X[((long)b * NPIX + rr) * CE + c];
  else if (rr < NPIX + KFG) v = (float)fg[((long)b * KFG + (rr - NPIX)) * CE + c];
  else v = (float)bg[((long)b * KBG + (rr - NPIX - KFG)) * CE + c];
  out[i] = v;
}

extern "C" void kernel_launch(void* const* d_in, const int* in_sizes, int n_in,
                              void* d_out, int out_size, void* d_ws, size_t ws_size,
                              hipStream_t stream) {
  (void)in_sizes; (void)n_in; (void)out_size; (void)ws_size;
  const float* s_x  = (const float*)d_in[0];
  const float* s_pm = (const float*)d_in[1];
  const float* s_sm = (const float*)d_in[2];
  const float* Wv   = (const float*)d_in[3];
  const float* bv   = (const float*)d_in[4];
  const float* Woff = (const float*)d_in[5];
  const float* boff = (const float*)d_in[6];
  const float* Wa   = (const float*)d_in[7];
  const float* ba   = (const float*)d_in[8];
  const float* Wout = (const float*)d_in[9];
  const float* bout = (const float*)d_in[10];
  const float* ln1g = (const float*)d_in[11];
  const float* ln1b = (const float*)d_in[12];
  const float* Wf1  = (const float*)d_in[13];
  const float* Wf2  = (const float*)d_in[14];
  const float* ln2g = (const float*)d_in[15];
  const float* ln2b = (const float*)d_in[16];
  float* out = (float*)d_out;
  char* pb = (char*)d_ws;

  const long BN  = (long)NB * NPIX;      // 16384
  const long BNC = BN * CE;              // 6291456

  float* X    = (float*)pb; pb += BNC * 4;
  float* POS  = (float*)pb; pb += BNC * 4;
  float* V    = (float*)pb; pb += BNC * 4;
  float* T1   = (float*)pb; pb += BNC * 4;
  float* T2   = (float*)pb; pb += BNC * 4;
  float* OFFB = (float*)pb; pb += BN * 216 * 4;
  float* AWB  = (float*)pb; pb += BN * 108 * 4;
  float* Z    = OFFB;  // FFN hidden chunk (4096*1152) aliases dead OFF/AW region
  float* padf = (float*)pb; pb += BN * 4;
  float* objf = (float*)pb; pb += BN * 4;
  float* notp = (float*)pb; pb += BN * 4;
  float* wfg  = (float*)pb; pb += BN * 4;
  float* wbg  = (float*)pb; pb += BN * 4;
  // fp64 region (8-byte aligned: all sizes above are multiples of 8 bytes... ensure)
  pb = (char*)(((size_t)pb + 7) & ~(size_t)7);
  double* xsq  = (double*)pb; pb += BN * 8;
  double* cFgA = (double*)pb; pb += (long)NB * KFG * CE * 8;
  double* cFgB = (double*)pb; pb += (long)NB * KFG * CE * 8;
  double* cBgA = (double*)pb; pb += (long)NB * KBG * CE * 8;
  double* cBgB = (double*)pb; pb += (long)NB * KBG * CE * 8;
  double* num  = (double*)pb; pb += (long)NB * KBG * CE * 8;
  double* den  = (double*)pb; pb += NB * KBG * 8;

  int bn = (int)BN;

  k_masks<<<(bn + 255) / 256, 256, 0, stream>>>(s_pm, s_sm, padf, objf, notp, wfg, wbg);
  k_transpose<<<(int)((BNC + 255) / 256), 256, 0, stream>>>(s_x, X);
  k_xsq<<<bn, 64, 0, stream>>>(X, xsq);
  k_pos<<<NB * HDIM, 256, 0, stream>>>(padf, POS);

  // ---- kmeans fg ----
  double* fgC; double* bgC;
  {
    double* src = cFgA; double* dst = cFgB;
    k_kinit<<<NB, 256, 0, stream>>>(X, wfg, src, KFG);
    for (int it = 0; it < NITER; ++it) {
      int na = NB * KFG * CE, nd = NB * KFG;
      k_zero64<<<(na + nd + 255) / 256, 256, 0, stream>>>(num, den, na, nd);
      k_assign_acc<KFG, KFG><<<dim3(NPIX / 256, NB), 256, 0, stream>>>(X, wfg, xsq, src, num, den);
      k_final<<<(na + 255) / 256, 256, 0, stream>>>(num, den, src, dst, na);
      double* tmp = src; src = dst; dst = tmp;
    }
    fgC = src;
  }
  // ---- kmeans bg ----
  {
    double* src = cBgA; double* dst = cBgB;
    k_kinit<<<NB, 256, 0, stream>>>(X, wbg, src, KBG);
    for (int it = 0; it < NITER; ++it) {
      int na = NB * KBG * CE, nd = NB * KBG;
      k_zero64<<<(na + nd + 255) / 256, 256, 0, stream>>>(num, den, na, nd);
      k_assign_acc<KBG, 25><<<dim3(NPIX / 256, NB), 256, 0, stream>>>(X, wbg, xsq, src, num, den);
      k_final<<<(na + 255) / 256, 256, 0, stream>>>(num, den, src, dst, na);
      double* tmp = src; src = dst; dst = tmp;
    }
    bgC = src;
  }

  // ---- layers ----
  for (int l = 0; l < NLAYERS; ++l) {
    const float* Wv_l   = Wv   + (long)l * CE * CE;
    const float* bv_l   = bv   + l * CE;
    const float* Woff_l = Woff + (long)l * CE * 216;
    const float* boff_l = boff + l * 216;
    const float* Wa_l   = Wa   + (long)l * CE * 108;
    const float* ba_l   = ba   + l * 108;
    const float* Wout_l = Wout + (long)l * CE * CE;
    const float* bout_l = bout + l * CE;
    const float* Wf1_l  = Wf1  + (long)l * CE * 1152;
    const float* Wf2_l  = Wf2  + (long)l * 1152 * CE;

    k_gemm<<<dim3(CE / 64, bn / 64), 256, 0, stream>>>(
        X, (const float*)nullptr, notp, Wv_l, bv_l, V, bn, CE, CE, 0);
    k_gemm<<<dim3(4, bn / 64), 256, 0, stream>>>(
        X, POS, (const float*)nullptr, Woff_l, boff_l, OFFB, bn, CE, 216, 0);
    k_gemm<<<dim3(2, bn / 64), 256, 0, stream>>>(
        X, POS, (const float*)nullptr, Wa_l, ba_l, AWB, bn, CE, 108, 0);
    k_softmax<<<(int)((BN * NH + 255) / 256), 256, 0, stream>>>(AWB);
    k_sample<<<(int)((BNC + 255) / 256), 256, 0, stream>>>(V, OFFB, AWB, T1);
    k_gemm<<<dim3(CE / 64, bn / 64), 256, 0, stream>>>(
        T1, (const float*)nullptr, (const float*)nullptr, Wout_l, bout_l, T2, bn, CE, CE, 0);
    k_ln<<<bn, 64, 0, stream>>>(X, T2, ln1g + l * CE, ln1b + l * CE);
    for (int ch = 0; ch < 4; ++ch) {
      float* Xc  = X  + (long)ch * 4096 * CE;
      float* T2c = T2 + (long)ch * 4096 * CE;
      k_gemm<<<dim3(1152 / 64, 64), 256, 0, stream>>>(
          Xc, (const float*)nullptr, (const float*)nullptr, Wf1_l, (const float*)nullptr,
          Z, 4096, CE, 1152, 1);
      k_gemm<<<dim3(CE / 64, 64), 256, 0, stream>>>(
          Z, (const float*)nullptr, (const float*)nullptr, Wf2_l, (const float*)nullptr,
          T2c, 4096, 1152, CE, 0);
    }
    k_ln<<<bn, 64, 0, stream>>>(X, T2, ln2g + l * CE, ln2b + l * CE);
  }

  k_out<<<(int)(((long)NB * (NPIX + KFG + KBG) * CE + 255) / 256), 256, 0, stream>>>(
      X, fgC, bgC, out);
}

// Round 3
// 8694.053 us; speedup vs baseline: 1.6911x; 1.6911x over previous
//
#include <hip/hip_runtime.h>
#include <math.h>

#define NB 4
#define CE 384
#define NH 12
#define DH 32
#define NPTS 9
#define NLAYERS 2
#define KFG 20
#define KBG 50
#define NITER 10
#define HDIM 64
#define WDIM 64
#define NPIX 4096
#define TWO_PI 6.283185307179586f

// ---------------- masks ----------------
__global__ void k_masks(const float* __restrict__ pm, const float* __restrict__ sm,
                        float* padf, float* objf, float* notp, float* wfg, float* wbg) {
  int i = blockIdx.x * 256 + threadIdx.x;
  if (i >= NB * NPIX) return;
  float p  = (pm[i] == 255.0f) ? 1.f : 0.f;
  float o  = (sm[i] == 1.0f) ? 1.f : 0.f;
  float np_ = 1.f - p;
  padf[i] = p; objf[i] = o; notp[i] = np_;
  wfg[i] = o * np_;
  wbg[i] = (1.f - o) * np_;
}

// ---------------- transpose s_x [B,C,N] -> X [B,N,C] ----------------
__global__ void k_transpose(const float* __restrict__ sx, float* __restrict__ X) {
  long i = (long)blockIdx.x * 256 + threadIdx.x;
  if (i >= (long)NB * NPIX * CE) return;
  int c = (int)(i % CE);
  long r = i / CE;
  int n = (int)(r % NPIX);
  int b = (int)(r / NPIX);
  X[i] = sx[((long)b * CE + c) * NPIX + n];
}

// ---------------- xsq (fp64) ----------------
__global__ void k_xsq(const float* __restrict__ X, double* __restrict__ xsq) {
  int row = blockIdx.x; int t = threadIdx.x;
  const float* xr = X + (long)row * CE;
  double s = 0.0;
  for (int i = t; i < CE; i += 64) { double v = (double)xr[i]; s += v * v; }
  #pragma unroll
  for (int o = 32; o > 0; o >>= 1) s += __shfl_down(s, o, 64);
  if (t == 0) xsq[row] = s;
}

// ---------------- sine positional encoding ----------------
__global__ void k_pos(const float* __restrict__ padf, float* __restrict__ POS) {
  int b = blockIdx.x / HDIM, hh = blockIdx.x % HDIM;
  __shared__ float xv[WDIM], yv[WDIM];
  int t = threadIdx.x;
  if (t < WDIM) {
    int w = t;
    float cum = 0.f, tot = 0.f;
    for (int h2 = 0; h2 < HDIM; ++h2) {
      float nm = 1.f - padf[b * NPIX + h2 * WDIM + w];
      tot += nm;
      if (h2 <= hh) cum += nm;
    }
    yv[w] = cum / (tot + 1e-6f) * TWO_PI;
    float rtot = 0.f, myc = 0.f;
    for (int w2 = 0; w2 < WDIM; ++w2) {
      float nm = 1.f - padf[b * NPIX + hh * WDIM + w2];
      rtot += nm;
      if (w2 <= w) myc += nm;
    }
    xv[w] = myc / (rtot + 1e-6f) * TWO_PI;
  }
  __syncthreads();
  const int nf = CE / 2;  // 192
  for (int i = t; i < WDIM * CE; i += 256) {
    int w = i / CE, c = i % CE;
    int tt = (c < nf) ? c : c - nf;
    float p = (c < nf) ? yv[w] : xv[w];
    float dt = powf(10000.0f, (float)(2 * (tt / 2)) / (float)nf);
    float v = p / dt;
    float r = (tt & 1) ? cosf(v) : sinf(v);
    POS[((long)(b * NPIX + hh * WDIM)) * CE + i] = r;
  }
}

// ---------------- kmeans init: first-K in-group (then earliest out-group) ----------------
__global__ void k_kinit(const float* __restrict__ X, const float* __restrict__ wts,
                        double* __restrict__ cen, int K) {
  int b = blockIdx.x;
  __shared__ int idx[KBG];
  if (threadIdx.x == 0) {
    int cnt = 0;
    for (int n = 0; n < NPIX && cnt < K; ++n) if (wts[b * NPIX + n] > 0.f) idx[cnt++] = n;
    for (int n = 0; n < NPIX && cnt < K; ++n) if (!(wts[b * NPIX + n] > 0.f)) idx[cnt++] = n;
  }
  __syncthreads();
  for (int i = threadIdx.x; i < K * CE; i += blockDim.x) {
    int k = i / CE, c = i % CE;
    cen[((long)b * K + k) * CE + c] = (double)X[((long)b * NPIX + idx[k]) * CE + c];
  }
}

__global__ void k_zero64(double* a, double* b, int na, int nbn) {
  int i = blockIdx.x * 256 + threadIdx.x;
  if (i < na) a[i] = 0.0;
  else if (i - na < nbn) b[i - na] = 0.0;
}

// ---------------- kmeans assignment (fp64 exact distances), no heavy atomics ----------------
template <int K, int KC>
__global__ __launch_bounds__(256) void k_assign(
    const float* __restrict__ X, const float* __restrict__ wts,
    const double* __restrict__ xsq, const double* __restrict__ cen,
    int* __restrict__ assign, double* __restrict__ den) {
  int b = blockIdx.y;
  int n0 = blockIdx.x * 256;
  int t = threadIdx.x;
  int n = n0 + t;
  __shared__ double csq[K];
  __shared__ double ct[KC][33];
  __shared__ float xt[256][37];    // stride 37: conflict-free lane access (t*37 mod 32 covers all banks)
  __shared__ int hist[K];
  const double* cb = cen + (long)b * K * CE;
  if (t < K) {
    double s = 0.0;
    for (int c = 0; c < CE; ++c) { double v = cb[t * CE + c]; s += v * v; }
    csq[t] = s;
    hist[t] = 0;
  }
  double best = 1.0e300; int bi = 0;
  for (int kc = 0; kc < K; kc += KC) {
    int kn = (K - kc < KC) ? (K - kc) : KC;
    double acc[KC];
    #pragma unroll
    for (int k = 0; k < KC; ++k) acc[k] = 0.0;
    for (int c0 = 0; c0 < CE; c0 += 32) {
      __syncthreads();
      for (int i = t; i < 256 * 32; i += 256) {
        int rr = i >> 5, cc = i & 31;
        xt[rr][cc] = X[((long)b * NPIX + n0 + rr) * CE + c0 + cc];
      }
      for (int i = t; i < KC * 32; i += 256) {
        int k = i >> 5, cc = i & 31;
        if (k < kn) ct[k][cc] = cb[(long)(kc + k) * CE + c0 + cc];
      }
      __syncthreads();
      for (int cc = 0; cc < 32; ++cc) {
        double xv = (double)xt[t][cc];
        #pragma unroll
        for (int k = 0; k < KC; ++k) acc[k] += xv * ct[k][cc];
      }
    }
    double myxsq = xsq[b * NPIX + n];
    for (int k = 0; k < kn; ++k) {
      double d = myxsq - 2.0 * acc[k] + csq[kc + k];
      if (d < best) { best = d; bi = kc + k; }
    }
  }
  float w = wts[b * NPIX + n];
  int a = (w > 0.f) ? bi : -1;
  assign[b * NPIX + n] = a;
  __syncthreads();
  if (a >= 0) atomicAdd(&hist[a], 1);
  __syncthreads();
  if (t < K && hist[t] > 0) atomicAdd(&den[b * K + t], (double)hist[t]);
}

// ---------------- kmeans accumulate: channel-owner, race-free LDS partials ----------------
// grid: (NPIX/512, CE/128, NB), block 128. thread t owns channel c0+t.
template <int K>
__global__ __launch_bounds__(128) void k_reduce(
    const float* __restrict__ X, const int* __restrict__ assign,
    double* __restrict__ num) {
  int b = blockIdx.z;
  int c0 = blockIdx.y * 128;
  int n0 = blockIdx.x * 512;
  int t = threadIdx.x;
  __shared__ double part[K][128];
  __shared__ int sa[512];
  for (int k = 0; k < K; ++k) part[k][t] = 0.0;
  for (int i = t; i < 512; i += 128) sa[i] = assign[b * NPIX + n0 + i];
  __syncthreads();
  for (int i = 0; i < 512; ++i) {
    int a = sa[i];
    if (a >= 0) {
      float x = X[((long)b * NPIX + n0 + i) * CE + c0 + t];
      part[a][t] += (double)x;
    }
  }
  __syncthreads();
  for (int k = 0; k < K; ++k) {
    double v = part[k][t];
    if (v != 0.0) atomicAdd(&num[((long)(b * K + k)) * CE + c0 + t], v);
  }
}

__global__ void k_final(const double* __restrict__ num, const double* __restrict__ den,
                        const double* __restrict__ cOld, double* __restrict__ cNew, int total) {
  int i = blockIdx.x * 256 + threadIdx.x;
  if (i >= total) return;
  double d = den[i / CE];
  cNew[i] = (d > 0.0) ? num[i] / fmax(d, 1e-6) : cOld[i];
}

// ---------------- generic fp32 GEMM: C = op(A) @ W (+bias)(+relu) ----------------
__global__ __launch_bounds__(256) void k_gemm(
    const float* __restrict__ A, const float* __restrict__ A2, const float* __restrict__ rs,
    const float* __restrict__ W, const float* __restrict__ bias, float* __restrict__ C,
    int M, int K, int Nn, int act) {
  __shared__ float As[16][65];
  __shared__ float Bs[16][65];
  int m0 = blockIdx.y * 64, n0 = blockIdx.x * 64;
  int t = threadIdx.x;
  int tn = t & 15, tm = t >> 4;
  float acc[4][4] = {};
  for (int k0 = 0; k0 < K; k0 += 16) {
    for (int i = t; i < 64 * 16; i += 256) {
      int r = i >> 4, kk = i & 15;
      long ai = (long)(m0 + r) * K + k0 + kk;
      float v = A[ai];
      if (A2) v += A2[ai];
      if (rs) v *= rs[m0 + r];
      As[kk][r] = v;
    }
    for (int i = t; i < 16 * 64; i += 256) {
      int kk = i >> 6, nn = i & 63;
      int col = n0 + nn;
      Bs[kk][nn] = (col < Nn) ? W[(long)(k0 + kk) * Nn + col] : 0.f;
    }
    __syncthreads();
    #pragma unroll
    for (int kk = 0; kk < 16; ++kk) {
      float av[4], bv[4];
      #pragma unroll
      for (int i = 0; i < 4; ++i) av[i] = As[kk][tm + 16 * i];
      #pragma unroll
      for (int j = 0; j < 4; ++j) bv[j] = Bs[kk][tn + 16 * j];
      #pragma unroll
      for (int i = 0; i < 4; ++i)
        #pragma unroll
        for (int j = 0; j < 4; ++j) acc[i][j] += av[i] * bv[j];
    }
    __syncthreads();
  }
  #pragma unroll
  for (int i = 0; i < 4; ++i) {
    int m = m0 + tm + 16 * i;
    #pragma unroll
    for (int j = 0; j < 4; ++j) {
      int n = n0 + tn + 16 * j;
      if (n < Nn) {
        float v = acc[i][j];
        if (bias) v += bias[n];
        if (act) v = fmaxf(v, 0.f);
        C[(long)m * Nn + n] = v;
      }
    }
  }
}

// ---------------- softmax over 9 points ----------------
__global__ void k_softmax(float* __restrict__ aw) {
  long i = (long)blockIdx.x * 256 + threadIdx.x;
  if (i >= (long)NB * NPIX * NH) return;
  float* p = aw + i * NPTS;
  float m = p[0];
  #pragma unroll
  for (int j = 1; j < NPTS; ++j) m = fmaxf(m, p[j]);
  float e[NPTS]; float s = 0.f;
  #pragma unroll
  for (int j = 0; j < NPTS; ++j) { e[j] = expf(p[j] - m); s += e[j]; }
  float inv = 1.f / s;
  #pragma unroll
  for (int j = 0; j < NPTS; ++j) p[j] = e[j] * inv;
}

// ---------------- bilinear sampler + point-weighted sum ----------------
__device__ __forceinline__ float sampleV(const float* __restrict__ vb, int xi, int yi, int c) {
  bool valid = (xi >= 0) & (xi < WDIM) & (yi >= 0) & (yi < HDIM);
  int xc = min(max(xi, 0), WDIM - 1), yc = min(max(yi, 0), HDIM - 1);
  float g = vb[(long)(yc * WDIM + xc) * CE + c];
  return valid ? g : 0.f;
}

__global__ void k_sample(const float* __restrict__ V, const float* __restrict__ OFF,
                         const float* __restrict__ AW, float* __restrict__ ATT) {
  long gid = (long)blockIdx.x * 256 + threadIdx.x;
  if (gid >= (long)NB * NPIX * CE) return;
  int c = (int)(gid % CE);
  long r = gid / CE;
  int n = (int)(r % NPIX);
  int b = (int)(r / NPIX);
  int h = c >> 5;
  int hh = n >> 6, ww = n & 63;
  const float* offp = OFF + ((long)(b * NPIX + n)) * 216 + h * 18;
  const float* awp  = AW  + ((long)(b * NPIX + n)) * 108 + h * 9;
  const float* vb = V + ((long)b * NPIX) * CE;
  float refx = ((float)ww + 0.5f) / (float)WDIM;
  float refy = ((float)hh + 0.5f) / (float)HDIM;
  float acc = 0.f;
  #pragma unroll
  for (int p = 0; p < NPTS; ++p) {
    float ox = offp[p * 2 + 0], oy = offp[p * 2 + 1];
    float lx = refx + ox / (float)WDIM;
    float ly = refy + oy / (float)HDIM;
    float xs = lx * (float)WDIM - 0.5f;
    float ys = ly * (float)HDIM - 0.5f;
    float x0f = floorf(xs), y0f = floorf(ys);
    float wx = xs - x0f, wy = ys - y0f;
    int x0 = (int)x0f, y0 = (int)y0f;
    float g00 = sampleV(vb, x0,     y0,     c);
    float g01 = sampleV(vb, x0 + 1, y0,     c);
    float g10 = sampleV(vb, x0,     y0 + 1, c);
    float g11 = sampleV(vb, x0 + 1, y0 + 1, c);
    float bil = g00 * (1.f - wx) * (1.f - wy) + g01 * wx * (1.f - wy)
              + g10 * (1.f - wx) * wy + g11 * wx * wy;
    acc += awp[p] * bil;
  }
  ATT[gid] = acc;
}

// ---------------- LayerNorm(X + T) -> X (in place), one wave per row ----------------
__global__ void k_ln(float* __restrict__ X, const float* __restrict__ T,
                     const float* __restrict__ g, const float* __restrict__ bb) {
  int row = blockIdx.x; int t = threadIdx.x;
  float* xr = X + (long)row * CE;
  const float* tr = T + (long)row * CE;
  float v[6]; float s = 0.f;
  #pragma unroll
  for (int i = 0; i < 6; ++i) { v[i] = xr[t + 64 * i] + tr[t + 64 * i]; s += v[i]; }
  #pragma unroll
  for (int o = 32; o > 0; o >>= 1) s += __shfl_down(s, o, 64);
  s = __shfl(s, 0, 64);
  float m = s / (float)CE;
  float var = 0.f;
  #pragma unroll
  for (int i = 0; i < 6; ++i) { float d = v[i] - m; var += d * d; }
  #pragma unroll
  for (int o = 32; o > 0; o >>= 1) var += __shfl_down(var, o, 64);
  var = __shfl(var, 0, 64);
  float rst = rsqrtf(var / (float)CE + 1e-5f);
  #pragma unroll
  for (int i = 0; i < 6; ++i) { int c = t + 64 * i; xr[c] = (v[i] - m) * rst * g[c] + bb[c]; }
}

// ---------------- assemble output ----------------
__global__ void k_out(const float* __restrict__ X, const double* __restrict__ fg,
                      const double* __restrict__ bg, float* __restrict__ out) {
  long i = (long)blockIdx.x * 256 + threadIdx.x;
  const long tot = (long)NB * (NPIX + KFG + KBG) * CE;
  if (i >= tot) return;
  int c = (int)(i % CE);
  long r = i / CE;
  int rr = (int)(r % (NPIX + KFG + KBG));
  int b = (int)(r / (NPIX + KFG + KBG));
  float v;
  if (rr < NPIX) v = X[((long)b * NPIX + rr) * CE + c];
  else if (rr < NPIX + KFG) v = (float)fg[((long)b * KFG + (rr - NPIX)) * CE + c];
  else v = (float)bg[((long)b * KBG + (rr - NPIX - KFG)) * CE + c];
  out[i] = v;
}

extern "C" void kernel_launch(void* const* d_in, const int* in_sizes, int n_in,
                              void* d_out, int out_size, void* d_ws, size_t ws_size,
                              hipStream_t stream) {
  (void)in_sizes; (void)n_in; (void)out_size; (void)ws_size;
  const float* s_x  = (const float*)d_in[0];
  const float* s_pm = (const float*)d_in[1];
  const float* s_sm = (const float*)d_in[2];
  const float* Wv   = (const float*)d_in[3];
  const float* bv   = (const float*)d_in[4];
  const float* Woff = (const float*)d_in[5];
  const float* boff = (const float*)d_in[6];
  const float* Wa   = (const float*)d_in[7];
  const float* ba   = (const float*)d_in[8];
  const float* Wout = (const float*)d_in[9];
  const float* bout = (const float*)d_in[10];
  const float* ln1g = (const float*)d_in[11];
  const float* ln1b = (const float*)d_in[12];
  const float* Wf1  = (const float*)d_in[13];
  const float* Wf2  = (const float*)d_in[14];
  const float* ln2g = (const float*)d_in[15];
  const float* ln2b = (const float*)d_in[16];
  float* out = (float*)d_out;
  char* pb = (char*)d_ws;

  const long BN  = (long)NB * NPIX;      // 16384
  const long BNC = BN * CE;              // 6291456

  float* X    = (float*)pb; pb += BNC * 4;
  float* POS  = (float*)pb; pb += BNC * 4;
  float* V    = (float*)pb; pb += BNC * 4;
  float* T1   = (float*)pb; pb += BNC * 4;
  float* T2   = (float*)pb; pb += BNC * 4;
  float* OFFB = (float*)pb; pb += BN * 216 * 4;
  float* AWB  = (float*)pb; pb += BN * 108 * 4;
  float* Z    = OFFB;  // FFN hidden chunk (4096*1152) aliases dead OFF/AW region
  float* padf = (float*)pb; pb += BN * 4;
  float* objf = (float*)pb; pb += BN * 4;
  float* notp = (float*)pb; pb += BN * 4;
  float* wfg  = (float*)pb; pb += BN * 4;
  float* wbg  = (float*)pb; pb += BN * 4;
  int*   assign = (int*)pb; pb += BN * 4;
  pb = (char*)(((size_t)pb + 7) & ~(size_t)7);
  double* xsq  = (double*)pb; pb += BN * 8;
  double* cFgA = (double*)pb; pb += (long)NB * KFG * CE * 8;
  double* cFgB = (double*)pb; pb += (long)NB * KFG * CE * 8;
  double* cBgA = (double*)pb; pb += (long)NB * KBG * CE * 8;
  double* cBgB = (double*)pb; pb += (long)NB * KBG * CE * 8;
  double* num  = (double*)pb; pb += (long)NB * KBG * CE * 8;
  double* den  = (double*)pb; pb += NB * KBG * 8;

  int bn = (int)BN;

  k_masks<<<(bn + 255) / 256, 256, 0, stream>>>(s_pm, s_sm, padf, objf, notp, wfg, wbg);
  k_transpose<<<(int)((BNC + 255) / 256), 256, 0, stream>>>(s_x, X);
  k_xsq<<<bn, 64, 0, stream>>>(X, xsq);
  k_pos<<<NB * HDIM, 256, 0, stream>>>(padf, POS);

  // ---- kmeans fg ----
  double* fgC; double* bgC;
  {
    double* src = cFgA; double* dst = cFgB;
    k_kinit<<<NB, 256, 0, stream>>>(X, wfg, src, KFG);
    for (int it = 0; it < NITER; ++it) {
      int na = NB * KFG * CE, nd = NB * KFG;
      k_zero64<<<(na + nd + 255) / 256, 256, 0, stream>>>(num, den, na, nd);
      k_assign<KFG, KFG><<<dim3(NPIX / 256, NB), 256, 0, stream>>>(X, wfg, xsq, src, assign, den);
      k_reduce<KFG><<<dim3(NPIX / 512, CE / 128, NB), 128, 0, stream>>>(X, assign, num);
      k_final<<<(na + 255) / 256, 256, 0, stream>>>(num, den, src, dst, na);
      double* tmp = src; src = dst; dst = tmp;
    }
    fgC = src;
  }
  // ---- kmeans bg ----
  {
    double* src = cBgA; double* dst = cBgB;
    k_kinit<<<NB, 256, 0, stream>>>(X, wbg, src, KBG);
    for (int it = 0; it < NITER; ++it) {
      int na = NB * KBG * CE, nd = NB * KBG;
      k_zero64<<<(na + nd + 255) / 256, 256, 0, stream>>>(num, den, na, nd);
      k_assign<KBG, 25><<<dim3(NPIX / 256, NB), 256, 0, stream>>>(X, wbg, xsq, src, assign, den);
      k_reduce<KBG><<<dim3(NPIX / 512, CE / 128, NB), 128, 0, stream>>>(X, assign, num);
      k_final<<<(na + 255) / 256, 256, 0, stream>>>(num, den, src, dst, na);
      double* tmp = src; src = dst; dst = tmp;
    }
    bgC = src;
  }

  // ---- layers ----
  for (int l = 0; l < NLAYERS; ++l) {
    const float* Wv_l   = Wv   + (long)l * CE * CE;
    const float* bv_l   = bv   + l * CE;
    const float* Woff_l = Woff + (long)l * CE * 216;
    const float* boff_l = boff + l * 216;
    const float* Wa_l   = Wa   + (long)l * CE * 108;
    const float* ba_l   = ba   + l * 108;
    const float* Wout_l = Wout + (long)l * CE * CE;
    const float* bout_l = bout + l * CE;
    const float* Wf1_l  = Wf1  + (long)l * CE * 1152;
    const float* Wf2_l  = Wf2  + (long)l * 1152 * CE;

    k_gemm<<<dim3(CE / 64, bn / 64), 256, 0, stream>>>(
        X, (const float*)nullptr, notp, Wv_l, bv_l, V, bn, CE, CE, 0);
    k_gemm<<<dim3(4, bn / 64), 256, 0, stream>>>(
        X, POS, (const float*)nullptr, Woff_l, boff_l, OFFB, bn, CE, 216, 0);
    k_gemm<<<dim3(2, bn / 64), 256, 0, stream>>>(
        X, POS, (const float*)nullptr, Wa_l, ba_l, AWB, bn, CE, 108, 0);
    k_softmax<<<(int)((BN * NH + 255) / 256), 256, 0, stream>>>(AWB);
    k_sample<<<(int)((BNC + 255) / 256), 256, 0, stream>>>(V, OFFB, AWB, T1);
    k_gemm<<<dim3(CE / 64, bn / 64), 256, 0, stream>>>(
        T1, (const float*)nullptr, (const float*)nullptr, Wout_l, bout_l, T2, bn, CE, CE, 0);
    k_ln<<<bn, 64, 0, stream>>>(X, T2, ln1g + l * CE, ln1b + l * CE);
    for (int ch = 0; ch < 4; ++ch) {
      float* Xc  = X  + (long)ch * 4096 * CE;
      float* T2c = T2 + (long)ch * 4096 * CE;
      k_gemm<<<dim3(1152 / 64, 64), 256, 0, stream>>>(
          Xc, (const float*)nullptr, (const float*)nullptr, Wf1_l, (const float*)nullptr,
          Z, 4096, CE, 1152, 1);
      k_gemm<<<dim3(CE / 64, 64), 256, 0, stream>>>(
          Z, (const float*)nullptr, (const float*)nullptr, Wf2_l, (const float*)nullptr,
          T2c, 4096, 1152, CE, 0);
    }
    k_ln<<<bn, 64, 0, stream>>>(X, T2, ln2g + l * CE, ln2b + l * CE);
  }

  k_out<<<(int)(((long)NB * (NPIX + KFG + KBG) * CE + 255) / 256), 256, 0, stream>>>(
      X, fgC, bgC, out);
}

// Round 4
// 5737.093 us; speedup vs baseline: 2.5628x; 1.5154x over previous
//
#include <hip/hip_runtime.h>
#include <hip/hip_bf16.h>
#include <math.h>

#define NB 4
#define CE 384
#define NH 12
#define DH 32
#define NPTS 9
#define NLAYERS 2
#define KFG 20
#define KBG 50
#define NITER 10
#define HDIM 64
#define WDIM 64
#define NPIX 4096
#define TWO_PI 6.283185307179586f

typedef __attribute__((ext_vector_type(8))) short short8;
typedef __attribute__((ext_vector_type(4))) float float4v;

static __device__ __forceinline__ unsigned short f2bf(float f) {
  __hip_bfloat16 h = __float2bfloat16(f);
  return *reinterpret_cast<unsigned short*>(&h);
}
static __device__ __forceinline__ float bf2f(unsigned short u) {
  unsigned x = ((unsigned)u) << 16;
  return __uint_as_float(x);
}

// ---------------- masks ----------------
__global__ void k_masks(const float* __restrict__ pm, const float* __restrict__ sm,
                        float* padf, float* objf, float* notp, float* wfg, float* wbg) {
  int i = blockIdx.x * 256 + threadIdx.x;
  if (i >= NB * NPIX) return;
  float p  = (pm[i] == 255.0f) ? 1.f : 0.f;
  float o  = (sm[i] == 1.0f) ? 1.f : 0.f;
  float np_ = 1.f - p;
  padf[i] = p; objf[i] = o; notp[i] = np_;
  wfg[i] = o * np_;
  wbg[i] = (1.f - o) * np_;
}

// ---------------- transpose s_x [B,C,N] -> X [B,N,C] ----------------
__global__ void k_transpose(const float* __restrict__ sx, float* __restrict__ X) {
  long i = (long)blockIdx.x * 256 + threadIdx.x;
  if (i >= (long)NB * NPIX * CE) return;
  int c = (int)(i % CE);
  long r = i / CE;
  int n = (int)(r % NPIX);
  int b = (int)(r / NPIX);
  X[i] = sx[((long)b * CE + c) * NPIX + n];
}

// ---------------- xsq (fp64) ----------------
__global__ void k_xsq(const float* __restrict__ X, double* __restrict__ xsq) {
  int row = blockIdx.x; int t = threadIdx.x;
  const float* xr = X + (long)row * CE;
  double s = 0.0;
  for (int i = t; i < CE; i += 64) { double v = (double)xr[i]; s += v * v; }
  #pragma unroll
  for (int o = 32; o > 0; o >>= 1) s += __shfl_down(s, o, 64);
  if (t == 0) xsq[row] = s;
}

// ---------------- sine positional encoding ----------------
__global__ void k_pos(const float* __restrict__ padf, float* __restrict__ POS) {
  int b = blockIdx.x / HDIM, hh = blockIdx.x % HDIM;
  __shared__ float xv[WDIM], yv[WDIM];
  int t = threadIdx.x;
  if (t < WDIM) {
    int w = t;
    float cum = 0.f, tot = 0.f;
    for (int h2 = 0; h2 < HDIM; ++h2) {
      float nm = 1.f - padf[b * NPIX + h2 * WDIM + w];
      tot += nm;
      if (h2 <= hh) cum += nm;
    }
    yv[w] = cum / (tot + 1e-6f) * TWO_PI;
    float rtot = 0.f, myc = 0.f;
    for (int w2 = 0; w2 < WDIM; ++w2) {
      float nm = 1.f - padf[b * NPIX + hh * WDIM + w2];
      rtot += nm;
      if (w2 <= w) myc += nm;
    }
    xv[w] = myc / (rtot + 1e-6f) * TWO_PI;
  }
  __syncthreads();
  const int nf = CE / 2;  // 192
  for (int i = t; i < WDIM * CE; i += 256) {
    int w = i / CE, c = i % CE;
    int tt = (c < nf) ? c : c - nf;
    float p = (c < nf) ? yv[w] : xv[w];
    float dt = powf(10000.0f, (float)(2 * (tt / 2)) / (float)nf);
    float v = p / dt;
    float r = (tt & 1) ? cosf(v) : sinf(v);
    POS[((long)(b * NPIX + hh * WDIM)) * CE + i] = r;
  }
}

// ---------------- kmeans init ----------------
__global__ void k_kinit(const float* __restrict__ X, const float* __restrict__ wts,
                        double* __restrict__ cen, int K) {
  int b = blockIdx.x;
  __shared__ int idx[KBG];
  if (threadIdx.x == 0) {
    int cnt = 0;
    for (int n = 0; n < NPIX && cnt < K; ++n) if (wts[b * NPIX + n] > 0.f) idx[cnt++] = n;
    for (int n = 0; n < NPIX && cnt < K; ++n) if (!(wts[b * NPIX + n] > 0.f)) idx[cnt++] = n;
  }
  __syncthreads();
  for (int i = threadIdx.x; i < K * CE; i += blockDim.x) {
    int k = i / CE, c = i % CE;
    cen[((long)b * K + k) * CE + c] = (double)X[((long)b * NPIX + idx[k]) * CE + c];
  }
}

__global__ void k_zero64(double* a, double* b, int na, int nbn) {
  int i = blockIdx.x * 256 + threadIdx.x;
  if (i < na) a[i] = 0.0;
  else if (i - na < nbn) b[i - na] = 0.0;
}

// ---------------- kmeans assignment (fp64 exact distances) ----------------
template <int K, int KC>
__global__ __launch_bounds__(256) void k_assign(
    const float* __restrict__ X, const float* __restrict__ wts,
    const double* __restrict__ xsq, const double* __restrict__ cen,
    int* __restrict__ assign, double* __restrict__ den) {
  int b = blockIdx.y;
  int n0 = blockIdx.x * 256;
  int t = threadIdx.x;
  int n = n0 + t;
  __shared__ double csq[K];
  __shared__ double ct[KC][33];
  __shared__ float xt[256][37];
  __shared__ int hist[K];
  const double* cb = cen + (long)b * K * CE;
  if (t < K) {
    double s = 0.0;
    for (int c = 0; c < CE; ++c) { double v = cb[t * CE + c]; s += v * v; }
    csq[t] = s;
    hist[t] = 0;
  }
  double best = 1.0e300; int bi = 0;
  for (int kc = 0; kc < K; kc += KC) {
    int kn = (K - kc < KC) ? (K - kc) : KC;
    double acc[KC];
    #pragma unroll
    for (int k = 0; k < KC; ++k) acc[k] = 0.0;
    for (int c0 = 0; c0 < CE; c0 += 32) {
      __syncthreads();
      for (int i = t; i < 256 * 32; i += 256) {
        int rr = i >> 5, cc = i & 31;
        xt[rr][cc] = X[((long)b * NPIX + n0 + rr) * CE + c0 + cc];
      }
      for (int i = t; i < KC * 32; i += 256) {
        int k = i >> 5, cc = i & 31;
        if (k < kn) ct[k][cc] = cb[(long)(kc + k) * CE + c0 + cc];
      }
      __syncthreads();
      for (int cc = 0; cc < 32; ++cc) {
        double xv = (double)xt[t][cc];
        #pragma unroll
        for (int k = 0; k < KC; ++k) acc[k] += xv * ct[k][cc];
      }
    }
    double myxsq = xsq[b * NPIX + n];
    for (int k = 0; k < kn; ++k) {
      double d = myxsq - 2.0 * acc[k] + csq[kc + k];
      if (d < best) { best = d; bi = kc + k; }
    }
  }
  float w = wts[b * NPIX + n];
  int a = (w > 0.f) ? bi : -1;
  assign[b * NPIX + n] = a;
  __syncthreads();
  if (a >= 0) atomicAdd(&hist[a], 1);
  __syncthreads();
  if (t < K && hist[t] > 0) atomicAdd(&den[b * K + t], (double)hist[t]);
}

// ---------------- kmeans accumulate ----------------
template <int K>
__global__ __launch_bounds__(128) void k_reduce(
    const float* __restrict__ X, const int* __restrict__ assign,
    double* __restrict__ num) {
  int b = blockIdx.z;
  int c0 = blockIdx.y * 128;
  int n0 = blockIdx.x * 512;
  int t = threadIdx.x;
  __shared__ double part[K][128];
  __shared__ int sa[512];
  for (int k = 0; k < K; ++k) part[k][t] = 0.0;
  for (int i = t; i < 512; i += 128) sa[i] = assign[b * NPIX + n0 + i];
  __syncthreads();
  for (int i = 0; i < 512; ++i) {
    int a = sa[i];
    if (a >= 0) {
      float x = X[((long)b * NPIX + n0 + i) * CE + c0 + t];
      part[a][t] += (double)x;
    }
  }
  __syncthreads();
  for (int k = 0; k < K; ++k) {
    double v = part[k][t];
    if (v != 0.0) atomicAdd(&num[((long)(b * K + k)) * CE + c0 + t], v);
  }
}

__global__ void k_final(const double* __restrict__ num, const double* __restrict__ den,
                        const double* __restrict__ cOld, double* __restrict__ cNew, int total) {
  int i = blockIdx.x * 256 + threadIdx.x;
  if (i >= total) return;
  double d = den[i / CE];
  cNew[i] = (d > 0.0) ? num[i] / fmax(d, 1e-6) : cOld[i];
}

// ---------------- activation -> bf16 staging: out = bf16((A + A2) * rs) ----------------
__global__ void k_cvtA(const float* __restrict__ A, const float* __restrict__ A2,
                       const float* __restrict__ rs, unsigned short* __restrict__ out) {
  long i = (long)blockIdx.x * 256 + threadIdx.x;
  if (i >= (long)NB * NPIX * CE) return;
  float v = A[i];
  if (A2) v += A2[i];
  if (rs) v *= rs[i / CE];
  out[i] = f2bf(v);
}

// ---------------- weight transpose + cast: Wt[n][k] = bf16(W[k][n]), zero-pad n>=N ----------------
__global__ void k_cvtW(const float* __restrict__ W, unsigned short* __restrict__ Wt,
                       int K, int N, int Npad) {
  int i = blockIdx.x * 256 + threadIdx.x;
  if (i >= Npad * K) return;
  int n = i / K, k = i % K;
  Wt[i] = (n < N) ? f2bf(W[(long)k * N + n]) : (unsigned short)0;
}

// ---------------- bf16 MFMA GEMM: C = A @ Bt^T (+bias)(+relu) ----------------
// A [M,K] bf16 row-major; Bt [Npad,K] bf16 (weight transposed). Block tile 128x128,
// 4 waves of 64x64, v_mfma_f32_16x16x32_bf16, BK=32. LDS stride 40 shorts (2-way free).
__global__ __launch_bounds__(256) void k_gemm_bf(
    const unsigned short* __restrict__ A, const unsigned short* __restrict__ Bt,
    const float* __restrict__ bias, float* __restrict__ Cf, unsigned short* __restrict__ Cb,
    int M, int K, int N, int relu) {
  __shared__ unsigned short As[128 * 40];
  __shared__ unsigned short Bs[128 * 40];
  int m0 = blockIdx.y * 128, n0 = blockIdx.x * 128;
  int t = threadIdx.x;
  int w = t >> 6, l = t & 63;
  int wm = w >> 1, wn = w & 1;
  int half = l >> 4, lr = l & 15;
  float4v acc[4][4] = {};
  for (int k0 = 0; k0 < K; k0 += 32) {
    for (int c = t; c < 512; c += 256) {
      int r = c >> 2, part = c & 3;
      uint4 va = *(const uint4*)(A + (size_t)(m0 + r) * K + k0 + part * 8);
      *(uint4*)(&As[r * 40 + part * 8]) = va;
      uint4 vb = *(const uint4*)(Bt + (size_t)(n0 + r) * K + k0 + part * 8);
      *(uint4*)(&Bs[r * 40 + part * 8]) = vb;
    }
    __syncthreads();
    short8 af[4], bfr[4];
    #pragma unroll
    for (int am = 0; am < 4; ++am)
      af[am] = *(const short8*)(&As[(wm * 64 + am * 16 + lr) * 40 + half * 8]);
    #pragma unroll
    for (int bn = 0; bn < 4; ++bn)
      bfr[bn] = *(const short8*)(&Bs[(wn * 64 + bn * 16 + lr) * 40 + half * 8]);
    #pragma unroll
    for (int am = 0; am < 4; ++am)
      #pragma unroll
      for (int bn = 0; bn < 4; ++bn)
        acc[am][bn] = __builtin_amdgcn_mfma_f32_16x16x32_bf16(af[am], bfr[bn], acc[am][bn], 0, 0, 0);
    __syncthreads();
  }
  #pragma unroll
  for (int am = 0; am < 4; ++am) {
    #pragma unroll
    for (int bn = 0; bn < 4; ++bn) {
      int gc = n0 + wn * 64 + bn * 16 + lr;
      if (gc < N) {
        float bv = bias ? bias[gc] : 0.f;
        int gr0 = m0 + wm * 64 + am * 16 + half * 4;
        #pragma unroll
        for (int r = 0; r < 4; ++r) {
          float v = acc[am][bn][r] + bv;
          if (relu) v = fmaxf(v, 0.f);
          size_t oi = (size_t)(gr0 + r) * N + gc;
          if (Cf) Cf[oi] = v;
          else Cb[oi] = f2bf(v);
        }
      }
    }
  }
}

// ---------------- softmax over 9 points (bf16 in/out) ----------------
__global__ void k_softmax(unsigned short* __restrict__ aw) {
  long i = (long)blockIdx.x * 256 + threadIdx.x;
  if (i >= (long)NB * NPIX * NH) return;
  unsigned short* p = aw + i * NPTS;
  float f[NPTS];
  #pragma unroll
  for (int j = 0; j < NPTS; ++j) f[j] = bf2f(p[j]);
  float m = f[0];
  #pragma unroll
  for (int j = 1; j < NPTS; ++j) m = fmaxf(m, f[j]);
  float s = 0.f;
  #pragma unroll
  for (int j = 0; j < NPTS; ++j) { f[j] = expf(f[j] - m); s += f[j]; }
  float inv = 1.f / s;
  #pragma unroll
  for (int j = 0; j < NPTS; ++j) p[j] = f2bf(f[j] * inv);
}

// ---------------- bilinear sampler + point-weighted sum (bf16 off/aw, bf16 out) ----------------
__device__ __forceinline__ float sampleV(const float* __restrict__ vb, int xi, int yi, int c) {
  bool valid = (xi >= 0) & (xi < WDIM) & (yi >= 0) & (yi < HDIM);
  int xc = min(max(xi, 0), WDIM - 1), yc = min(max(yi, 0), HDIM - 1);
  float g = vb[(long)(yc * WDIM + xc) * CE + c];
  return valid ? g : 0.f;
}

__global__ void k_sample(const float* __restrict__ V, const unsigned short* __restrict__ OFF,
                         const unsigned short* __restrict__ AW, unsigned short* __restrict__ ATT) {
  long gid = (long)blockIdx.x * 256 + threadIdx.x;
  if (gid >= (long)NB * NPIX * CE) return;
  int c = (int)(gid % CE);
  long r = gid / CE;
  int n = (int)(r % NPIX);
  int b = (int)(r / NPIX);
  int h = c >> 5;
  int hh = n >> 6, ww = n & 63;
  const unsigned short* offp = OFF + ((long)(b * NPIX + n)) * 216 + h * 18;
  const unsigned short* awp  = AW  + ((long)(b * NPIX + n)) * 108 + h * 9;
  const float* vb = V + ((long)b * NPIX) * CE;
  float refx = ((float)ww + 0.5f) / (float)WDIM;
  float refy = ((float)hh + 0.5f) / (float)HDIM;
  float acc = 0.f;
  #pragma unroll
  for (int p = 0; p < NPTS; ++p) {
    float ox = bf2f(offp[p * 2 + 0]), oy = bf2f(offp[p * 2 + 1]);
    float lx = refx + ox / (float)WDIM;
    float ly = refy + oy / (float)HDIM;
    float xs = lx * (float)WDIM - 0.5f;
    float ys = ly * (float)HDIM - 0.5f;
    float x0f = floorf(xs), y0f = floorf(ys);
    float wx = xs - x0f, wy = ys - y0f;
    int x0 = (int)x0f, y0 = (int)y0f;
    float g00 = sampleV(vb, x0,     y0,     c);
    float g01 = sampleV(vb, x0 + 1, y0,     c);
    float g10 = sampleV(vb, x0,     y0 + 1, c);
    float g11 = sampleV(vb, x0 + 1, y0 + 1, c);
    float bil = g00 * (1.f - wx) * (1.f - wy) + g01 * wx * (1.f - wy)
              + g10 * (1.f - wx) * wy + g11 * wx * wy;
    acc += bf2f(awp[p]) * bil;
  }
  ATT[gid] = f2bf(acc);
}

// ---------------- LayerNorm(X + T) -> X (in place), one wave per row ----------------
__global__ void k_ln(float* __restrict__ X, const float* __restrict__ T,
                     const float* __restrict__ g, const float* __restrict__ bb) {
  int row = blockIdx.x; int t = threadIdx.x;
  float* xr = X + (long)row * CE;
  const float* tr = T + (long)row * CE;
  float v[6]; float s = 0.f;
  #pragma unroll
  for (int i = 0; i < 6; ++i) { v[i] = xr[t + 64 * i] + tr[t + 64 * i]; s += v[i]; }
  #pragma unroll
  for (int o = 32; o > 0; o >>= 1) s += __shfl_down(s, o, 64);
  s = __shfl(s, 0, 64);
  float m = s / (float)CE;
  float var = 0.f;
  #pragma unroll
  for (int i = 0; i < 6; ++i) { float d = v[i] - m; var += d * d; }
  #pragma unroll
  for (int o = 32; o > 0; o >>= 1) var += __shfl_down(var, o, 64);
  var = __shfl(var, 0, 64);
  float rst = rsqrtf(var / (float)CE + 1e-5f);
  #pragma unroll
  for (int i = 0; i < 6; ++i) { int c = t + 64 * i; xr[c] = (v[i] - m) * rst * g[c] + bb[c]; }
}

// ---------------- assemble output ----------------
__global__ void k_out(const float* __restrict__ X, const double* __restrict__ fg,
                      const double* __restrict__ bg, float* __restrict__ out) {
  long i = (long)blockIdx.x * 256 + threadIdx.x;
  const long tot = (long)NB * (NPIX + KFG + KBG) * CE;
  if (i >= tot) return;
  int c = (int)(i % CE);
  long r = i / CE;
  int rr = (int)(r % (NPIX + KFG + KBG));
  int b = (int)(r / (NPIX + KFG + KBG));
  float v;
  if (rr < NPIX) v = X[((long)b * NPIX + rr) * CE + c];
  else if (rr < NPIX + KFG) v = (float)fg[((long)b * KFG + (rr - NPIX)) * CE + c];
  else v = (float)bg[((long)b * KBG + (rr - NPIX - KFG)) * CE + c];
  out[i] = v;
}

extern "C" void kernel_launch(void* const* d_in, const int* in_sizes, int n_in,
                              void* d_out, int out_size, void* d_ws, size_t ws_size,
                              hipStream_t stream) {
  (void)in_sizes; (void)n_in; (void)out_size; (void)ws_size;
  const float* s_x  = (const float*)d_in[0];
  const float* s_pm = (const float*)d_in[1];
  const float* s_sm = (const float*)d_in[2];
  const float* Wv   = (const float*)d_in[3];
  const float* bv   = (const float*)d_in[4];
  const float* Woff = (const float*)d_in[5];
  const float* boff = (const float*)d_in[6];
  const float* Wa   = (const float*)d_in[7];
  const float* ba   = (const float*)d_in[8];
  const float* Wout = (const float*)d_in[9];
  const float* bout = (const float*)d_in[10];
  const float* ln1g = (const float*)d_in[11];
  const float* ln1b = (const float*)d_in[12];
  const float* Wf1  = (const float*)d_in[13];
  const float* Wf2  = (const float*)d_in[14];
  const float* ln2g = (const float*)d_in[15];
  const float* ln2b = (const float*)d_in[16];
  float* out = (float*)d_out;
  char* pb = (char*)d_ws;

  const long BN  = (long)NB * NPIX;      // 16384
  const long BNC = BN * CE;              // 6291456

  float* X    = (float*)pb; pb += BNC * 4;
  float* POS  = (float*)pb; pb += BNC * 4;
  float* V    = (float*)pb; pb += BNC * 4;
  float* T2   = (float*)pb; pb += BNC * 4;
  // bf16 staging; Zbf (16384x1152) aliases QB+VBin+T1b (3 x 16384x384 = same bytes)
  unsigned short* QB   = (unsigned short*)pb; pb += BNC * 2;
  unsigned short* VBin = (unsigned short*)pb; pb += BNC * 2;
  unsigned short* T1b  = (unsigned short*)pb; pb += BNC * 2;
  unsigned short* Zbf  = QB;
  unsigned short* XB   = (unsigned short*)pb; pb += BNC * 2;
  unsigned short* OFFb = (unsigned short*)pb; pb += BN * 216 * 2;
  unsigned short* AWb  = (unsigned short*)pb; pb += BN * 108 * 2;
  // transposed bf16 weights per layer: Npad x K
  const int S_WV = 384 * 384, S_WOFF = 256 * 384, S_WA = 128 * 384,
            S_WOUT = 384 * 384, S_WF1 = 1152 * 384, S_WF2 = 384 * 1152;
  unsigned short* WT[NLAYERS][6];
  for (int l = 0; l < NLAYERS; ++l) {
    WT[l][0] = (unsigned short*)pb; pb += S_WV * 2;
    WT[l][1] = (unsigned short*)pb; pb += S_WOFF * 2;
    WT[l][2] = (unsigned short*)pb; pb += S_WA * 2;
    WT[l][3] = (unsigned short*)pb; pb += S_WOUT * 2;
    WT[l][4] = (unsigned short*)pb; pb += S_WF1 * 2;
    WT[l][5] = (unsigned short*)pb; pb += S_WF2 * 2;
  }
  float* padf = (float*)pb; pb += BN * 4;
  float* objf = (float*)pb; pb += BN * 4;
  float* notp = (float*)pb; pb += BN * 4;
  float* wfg  = (float*)pb; pb += BN * 4;
  float* wbg  = (float*)pb; pb += BN * 4;
  int*   assign = (int*)pb; pb += BN * 4;
  pb = (char*)(((size_t)pb + 7) & ~(size_t)7);
  double* xsq  = (double*)pb; pb += BN * 8;
  double* cFgA = (double*)pb; pb += (long)NB * KFG * CE * 8;
  double* cFgB = (double*)pb; pb += (long)NB * KFG * CE * 8;
  double* cBgA = (double*)pb; pb += (long)NB * KBG * CE * 8;
  double* cBgB = (double*)pb; pb += (long)NB * KBG * CE * 8;
  double* num  = (double*)pb; pb += (long)NB * KBG * CE * 8;
  double* den  = (double*)pb; pb += NB * KBG * 8;

  int bn = (int)BN;
  int cvtBlocks = (int)((BNC + 255) / 256);

  k_masks<<<(bn + 255) / 256, 256, 0, stream>>>(s_pm, s_sm, padf, objf, notp, wfg, wbg);
  k_transpose<<<cvtBlocks, 256, 0, stream>>>(s_x, X);
  k_xsq<<<bn, 64, 0, stream>>>(X, xsq);
  k_pos<<<NB * HDIM, 256, 0, stream>>>(padf, POS);

  // ---- weight transposes (bf16) ----
  for (int l = 0; l < NLAYERS; ++l) {
    k_cvtW<<<(S_WV + 255) / 256, 256, 0, stream>>>(Wv + (long)l * CE * CE, WT[l][0], CE, 384, 384);
    k_cvtW<<<(S_WOFF + 255) / 256, 256, 0, stream>>>(Woff + (long)l * CE * 216, WT[l][1], CE, 216, 256);
    k_cvtW<<<(S_WA + 255) / 256, 256, 0, stream>>>(Wa + (long)l * CE * 108, WT[l][2], CE, 108, 128);
    k_cvtW<<<(S_WOUT + 255) / 256, 256, 0, stream>>>(Wout + (long)l * CE * CE, WT[l][3], CE, 384, 384);
    k_cvtW<<<(S_WF1 + 255) / 256, 256, 0, stream>>>(Wf1 + (long)l * CE * 1152, WT[l][4], CE, 1152, 1152);
    k_cvtW<<<(S_WF2 + 255) / 256, 256, 0, stream>>>(Wf2 + (long)l * 1152 * CE, WT[l][5], 1152, 384, 384);
  }

  // ---- kmeans fg ----
  double* fgC; double* bgC;
  {
    double* src = cFgA; double* dst = cFgB;
    k_kinit<<<NB, 256, 0, stream>>>(X, wfg, src, KFG);
    for (int it = 0; it < NITER; ++it) {
      int na = NB * KFG * CE, nd = NB * KFG;
      k_zero64<<<(na + nd + 255) / 256, 256, 0, stream>>>(num, den, na, nd);
      k_assign<KFG, KFG><<<dim3(NPIX / 256, NB), 256, 0, stream>>>(X, wfg, xsq, src, assign, den);
      k_reduce<KFG><<<dim3(NPIX / 512, CE / 128, NB), 128, 0, stream>>>(X, assign, num);
      k_final<<<(na + 255) / 256, 256, 0, stream>>>(num, den, src, dst, na);
      double* tmp = src; src = dst; dst = tmp;
    }
    fgC = src;
  }
  // ---- kmeans bg ----
  {
    double* src = cBgA; double* dst = cBgB;
    k_kinit<<<NB, 256, 0, stream>>>(X, wbg, src, KBG);
    for (int it = 0; it < NITER; ++it) {
      int na = NB * KBG * CE, nd = NB * KBG;
      k_zero64<<<(na + nd + 255) / 256, 256, 0, stream>>>(num, den, na, nd);
      k_assign<KBG, 25><<<dim3(NPIX / 256, NB), 256, 0, stream>>>(X, wbg, xsq, src, assign, den);
      k_reduce<KBG><<<dim3(NPIX / 512, CE / 128, NB), 128, 0, stream>>>(X, assign, num);
      k_final<<<(na + 255) / 256, 256, 0, stream>>>(num, den, src, dst, na);
      double* tmp = src; src = dst; dst = tmp;
    }
    bgC = src;
  }

  // ---- layers ----
  for (int l = 0; l < NLAYERS; ++l) {
    const float* bv_l   = bv   + l * CE;
    const float* boff_l = boff + l * 216;
    const float* ba_l   = ba   + l * 108;
    const float* bout_l = bout + l * CE;

    // staging conversions
    k_cvtA<<<cvtBlocks, 256, 0, stream>>>(X, POS, (const float*)nullptr, QB);       // q = x+pos
    k_cvtA<<<cvtBlocks, 256, 0, stream>>>(X, (const float*)nullptr, notp, VBin);    // x*notpad
    // V = VBin @ WvT + bv  (fp32 out)
    k_gemm_bf<<<dim3(3, 128), 256, 0, stream>>>(VBin, WT[l][0], bv_l, V, (unsigned short*)nullptr,
                                                bn, CE, 384, 0);
    // OFF = QB @ WoffT + boff (bf16 out)
    k_gemm_bf<<<dim3(2, 128), 256, 0, stream>>>(QB, WT[l][1], boff_l, (float*)nullptr, OFFb,
                                                bn, CE, 216, 0);
    // AW = QB @ WaT + ba (bf16 out)
    k_gemm_bf<<<dim3(1, 128), 256, 0, stream>>>(QB, WT[l][2], ba_l, (float*)nullptr, AWb,
                                                bn, CE, 108, 0);
    k_softmax<<<(int)((BN * NH + 255) / 256), 256, 0, stream>>>(AWb);
    k_sample<<<cvtBlocks, 256, 0, stream>>>(V, OFFb, AWb, T1b);
    // T2 = T1 @ WoutT + bout (fp32 out)
    k_gemm_bf<<<dim3(3, 128), 256, 0, stream>>>(T1b, WT[l][3], bout_l, T2, (unsigned short*)nullptr,
                                                bn, CE, 384, 0);
    k_ln<<<bn, 64, 0, stream>>>(X, T2, ln1g + l * CE, ln1b + l * CE);
    // FFN: Z = relu(X @ Wf1T) (bf16 out, aliases QB/VBin/T1b), T2 = Z @ Wf2T (fp32)
    k_cvtA<<<cvtBlocks, 256, 0, stream>>>(X, (const float*)nullptr, (const float*)nullptr, XB);
    k_gemm_bf<<<dim3(9, 128), 256, 0, stream>>>(XB, WT[l][4], (const float*)nullptr,
                                                (float*)nullptr, Zbf, bn, CE, 1152, 1);
    k_gemm_bf<<<dim3(3, 128), 256, 0, stream>>>(Zbf, WT[l][5], (const float*)nullptr,
                                                T2, (unsigned short*)nullptr, bn, 1152, 384, 0);
    k_ln<<<bn, 64, 0, stream>>>(X, T2, ln2g + l * CE, ln2b + l * CE);
  }

  k_out<<<(int)(((long)NB * (NPIX + KFG + KBG) * CE + 255) / 256), 256, 0, stream>>>(
      X, fgC, bgC, out);
}